// Round 3
// baseline (636.590 us; speedup 1.0000x reference)
//
#include <hip/hip_runtime.h>
#include <hip/hip_bf16.h>

// MHAGCN: x(4096,6,1024) f32 -> out(4096,6,256) f32. Internal bf16 + MFMA.
// R9: tail attack. GEMM is at its 9-round quantization floor (405us, 763 TF/
// round-rate); the ~205us tail (14 launches, 3 scores passes, small-block mid/
// out) is the target. (1) scores ride as light z-slices inside GEMM dispatches
// (pair2 rides the final dispatch's 0.75-round idle tail for free; pair1 adds
// ~6us to dispatch2) -- needs 4 extra Q/KV panels => big3 path (ws>=267MB),
// falls back to R8 flow otherwise. (2) head-4 scores fused into batch_mid
// (VALU dots, overlapped). (3) one prep kernel (cvt+4 transposes); mid/out at
// 256 thr x 4 batches. Verified 8-phase GEMM inner loop untouched.

using bf16 = __hip_bfloat16;
using s16x8 = __attribute__((ext_vector_type(8))) short;
using f32x4 = __attribute__((ext_vector_type(4))) float;

#define AS1(p) ((__attribute__((address_space(1))) void*)((void*)(p)))
#define AS3(p) ((__attribute__((address_space(3))) void*)(p))

#if defined(__has_builtin)
#if __has_builtin(__builtin_amdgcn_global_load_lds)
#define HAVE_GLL 1
#endif
#endif

__device__ __forceinline__ float s2f(short s) {
  union { unsigned int u; float f; } c;
  c.u = ((unsigned int)(unsigned short)s) << 16;
  return c.f;
}
__device__ __forceinline__ short f2s(float x) {
  bf16 b = __float2bfloat16(x);
  short s;
  __builtin_memcpy(&s, &b, 2);
  return s;
}

// GEMM output-routing job (selected per blockIdx.z)
struct GJob {
  const bf16* Bt;
  const float* bias;
  int boff;
  bf16* out;
};
// Embedded-scores job (light z-slices)
struct ScJob {
  const bf16* Q;
  const bf16* KV;
  float* S;
  int head;
};

// ---------------------------------------------------------------------------
// prep: cvt x->bf16 (blocks [0,12288)) + 4 weight transposes ([12288,18048))
// ---------------------------------------------------------------------------
__global__ __launch_bounds__(256) void prep_kernel(
    const float* __restrict__ x, bf16* __restrict__ Xb, int do_cvt,
    const float* __restrict__ aW1, bf16* __restrict__ W1T,
    const float* __restrict__ aW2, bf16* __restrict__ W2T,
    const float* __restrict__ gW1, bf16* __restrict__ G1T,
    const float* __restrict__ gW2, bf16* __restrict__ G2T) {
  const int bid = blockIdx.x, tid = threadIdx.x;
  if (bid < 12288) {
    if (!do_cvt) return;
    int i = bid * 256 + tid;  // < 3145728
    float4 p0 = ((const float4*)x)[i * 2];
    float4 p1 = ((const float4*)x)[i * 2 + 1];
    s16x8 v;
    v[0] = f2s(p0.x); v[1] = f2s(p0.y); v[2] = f2s(p0.z); v[3] = f2s(p0.w);
    v[4] = f2s(p1.x); v[5] = f2s(p1.y); v[6] = f2s(p1.z); v[7] = f2s(p1.w);
    ((s16x8*)Xb)[i] = v;
    return;
  }
  int r = bid - 12288;
  const float* src; short* dst; int R, C, bx, by;
  if (r < 2560) {
    int z = r >> 9, q = r & 511;
    src = aW1 + (size_t)z * 524288; dst = (short*)W1T + (size_t)z * 524288;
    R = 1024; C = 512; bx = q & 31; by = q >> 5;
  } else if (r < 5120) {
    r -= 2560;
    int z = r >> 9, q = r & 511;
    src = aW2 + (size_t)z * 524288; dst = (short*)W2T + (size_t)z * 524288;
    R = 1024; C = 512; bx = q & 31; by = q >> 5;
  } else if (r < 5632) {
    r -= 5120;
    src = gW1; dst = (short*)G1T; R = 1024; C = 512; bx = r & 31; by = r >> 5;
  } else {
    r -= 5632;
    src = gW2; dst = (short*)G2T; R = 512; C = 256; bx = r & 15; by = r >> 4;
  }
  __shared__ short tile[32][33];
  const int tx = tid & 31, ty = tid >> 5;  // (32, 8)
  const int r0 = bx * 32, c0 = by * 32;
#pragma unroll
  for (int i = 0; i < 4; ++i)
    tile[ty + i * 8][tx] = f2s(src[(size_t)(r0 + ty + i * 8) * C + c0 + tx]);
  __syncthreads();
#pragma unroll
  for (int i = 0; i < 4; ++i)
    dst[(size_t)(c0 + ty + i * 8) * R + r0 + tx] = tile[tx][ty + i * 8];
}

// ---------------------------------------------------------------------------
// scores wave body: 2 batches packed as rows {b0: 0-7, b1: 8-15} on BOTH m,n.
// Pad lanes (l16=6,7,14,15) duplicate a local row (L1-hot) instead of a
// remote clamp row. Valid outputs: diagonal blocks only.
// ---------------------------------------------------------------------------
__device__ __forceinline__ void scores_wave(
    const bf16* __restrict__ Q, const bf16* __restrict__ KV,
    float* __restrict__ S, int head, int b0, int lane) {
  const int l16 = lane & 15, quad = lane >> 4;
  const int lr0 = (l16 < 8) ? l16 : (l16 - 8);
  const int lr = (lr0 <= 5) ? lr0 : 5;
  const int gb = (l16 < 8) ? b0 : (b0 + 1);
  const int gr = gb * 6 + lr;

  const short* qrow = (const short*)Q + (size_t)gr * 512 + quad * 8;
  const short* krow = (const short*)KV + (size_t)gr * 512 + quad * 8;

  f32x4 acc = (f32x4){0.f, 0.f, 0.f, 0.f};
#pragma unroll
  for (int kk = 0; kk < 16; ++kk) {
    s16x8 a = *(const s16x8*)(qrow + kk * 32);
    s16x8 b = *(const s16x8*)(krow + kk * 32);
    acc = __builtin_amdgcn_mfma_f32_16x16x32_bf16(a, b, acc, 0, 0, 0);
  }

  if (l16 < 6) {  // n -> b0 KV rows
#pragma unroll
    for (int r = 0; r < 4; ++r) {
      int m = quad * 4 + r;
      if (m < 6)
        S[((size_t)b0 * 5 + head) * 36 + m * 6 + l16] = acc[r];
    }
  } else if (l16 >= 8 && l16 < 14) {  // n -> b1 KV rows
#pragma unroll
    for (int r = 0; r < 4; ++r) {
      int m = quad * 4 + r;
      if (m >= 8 && m < 14)
        S[((size_t)(b0 + 1) * 5 + head) * 36 + (m - 8) * 6 + (l16 - 8)] = acc[r];
    }
  }
}

// standalone scores (fallback paths); up to 2 heads via blockIdx.y
__global__ __launch_bounds__(256) void scores_mfma2(
    const bf16* __restrict__ Q0, const bf16* __restrict__ KV0,
    const bf16* __restrict__ Q1, const bf16* __restrict__ KV1,
    float* __restrict__ S, int head0) {
  const int h = blockIdx.y;
  const int lane = threadIdx.x & 63, w = threadIdx.x >> 6;
  const int b0 = (blockIdx.x * 4 + w) * 2;
  scores_wave(h ? Q1 : Q0, h ? KV1 : KV0, S, head0 + h, b0, lane);
}

// ---------------------------------------------------------------------------
// Legacy 128x128 GEMM (m97 structure) — small-ws fallback + the HW gemm
// (N=256: (192,2)=384 blocks -> better fill than 96 blocks of 256^2).
// ---------------------------------------------------------------------------
template <int AF32>
__global__ __launch_bounds__(256) void gemm_bt(
    const void* __restrict__ Ag,
    const bf16* __restrict__ Bt0, const bf16* __restrict__ Bt1,
    const float* __restrict__ bias0, const float* __restrict__ bias1, int boff,
    bf16* __restrict__ out0, bf16* __restrict__ out1,
    int M, int N, int K) {
  const bf16* Bt = (blockIdx.z == 0) ? Bt0 : Bt1;
  const float* bias = (blockIdx.z == 0) ? bias0 : bias1;
  bf16* Cg = (blockIdx.z == 0) ? out0 : out1;

  __shared__ short lA[128 * 32];
  __shared__ short lB[128 * 32];

  const int tid = threadIdx.x;
  const int lane = tid & 63, w = tid >> 6;
  const int wr = w >> 1, wc = w & 1;
  const int l16 = lane & 15, quad = lane >> 4;
  const int lrow = lane >> 2;
  const int scol = (((lane & 3) ^ ((lane >> 3) & 3)) * 8);

  const size_t rm0 = (size_t)blockIdx.x * 128;
  const size_t cn0 = (size_t)blockIdx.y * 128;

  f32x4 acc[4][4];
#pragma unroll
  for (int i = 0; i < 4; ++i)
#pragma unroll
    for (int j = 0; j < 4; ++j) acc[i][j] = (f32x4){0.f, 0.f, 0.f, 0.f};

  for (int kb = 0; kb < K; kb += 32) {
#pragma unroll
    for (int t = 0; t < 2; ++t) {
      int chunk = w * 2 + t;
      int row = chunk * 16 + lrow;
      const bf16* gb = Bt + (cn0 + row) * (size_t)K + kb + scol;
#ifdef HAVE_GLL
      __builtin_amdgcn_global_load_lds(AS1(gb), AS3(lB + chunk * 512), 16, 0, 0);
#else
      *(s16x8*)(lB + chunk * 512 + lane * 8) = *(const s16x8*)gb;
#endif
      if (AF32) {
        const float* ga = (const float*)Ag + (rm0 + row) * (size_t)K + kb + scol;
        float4 p0 = *(const float4*)ga;
        float4 p1 = *(const float4*)(ga + 4);
        s16x8 v;
        v[0] = f2s(p0.x); v[1] = f2s(p0.y); v[2] = f2s(p0.z); v[3] = f2s(p0.w);
        v[4] = f2s(p1.x); v[5] = f2s(p1.y); v[6] = f2s(p1.z); v[7] = f2s(p1.w);
        *(s16x8*)(lA + chunk * 512 + lane * 8) = v;
      } else {
        const bf16* ga = (const bf16*)Ag + (rm0 + row) * (size_t)K + kb + scol;
#ifdef HAVE_GLL
        __builtin_amdgcn_global_load_lds(AS1(ga), AS3(lA + chunk * 512), 16, 0, 0);
#else
        *(s16x8*)(lA + chunk * 512 + lane * 8) = *(const s16x8*)ga;
#endif
      }
    }
    __syncthreads();

    const int q2 = (quad ^ ((l16 >> 1) & 3)) * 8;
    s16x8 af[4], bfv[4];
#pragma unroll
    for (int i = 0; i < 4; ++i) {
      af[i] = *(const s16x8*)(lA + (wr * 64 + i * 16 + l16) * 32 + q2);
      bfv[i] = *(const s16x8*)(lB + (wc * 64 + i * 16 + l16) * 32 + q2);
    }
#pragma unroll
    for (int i = 0; i < 4; ++i)
#pragma unroll
      for (int j = 0; j < 4; ++j)
        acc[i][j] = __builtin_amdgcn_mfma_f32_16x16x32_bf16(af[i], bfv[j], acc[i][j], 0, 0, 0);
    __syncthreads();
  }

#pragma unroll
  for (int j = 0; j < 4; ++j) {
    size_t col = cn0 + wc * 64 + j * 16 + l16;
    float bv = bias ? bias[boff + col] : 0.f;
#pragma unroll
    for (int i = 0; i < 4; ++i) {
      size_t rowb = rm0 + wr * 64 + i * 16 + quad * 4;
#pragma unroll
      for (int r = 0; r < 4; ++r) {
        float v = acc[i][j][r] + bv;
        Cg[(rowb + r) * (size_t)N + col] = __float2bfloat16(v);
      }
    }
  }
}

// ---------------------------------------------------------------------------
// 256x256 8-phase GEMM (m201 template). Inner loop identical to R7/R8
// (verified). blockIdx.z >= nzg -> light scores slice (reads PREVIOUS
// dispatches' Q/KV panels; buffers are disjoint from this dispatch's outputs).
// ---------------------------------------------------------------------------
__global__ __launch_bounds__(512, 2) void gemm256_8ph(
    const bf16* __restrict__ A,
    GJob j0, GJob j1, GJob j2, GJob j3,
    int nzg, ScJob s0, ScJob s1,
    int M, int N, int K) {
  if ((int)blockIdx.z >= nzg) {
    ScJob sc = ((int)blockIdx.z == nzg) ? s0 : s1;
    const int lane = threadIdx.x & 63, w = threadIdx.x >> 6;
    const int stride = gridDim.x * gridDim.y * 8;
    const int base = ((int)blockIdx.y * gridDim.x + blockIdx.x) * 8 + w;
    for (int job = base; job < 2048; job += stride)
      scores_wave(sc.Q, sc.KV, sc.S, sc.head, job * 2, lane);
    return;
  }

  const GJob j = (blockIdx.z == 0) ? j0 : (blockIdx.z == 1) ? j1
               : (blockIdx.z == 2) ? j2 : j3;
  const bf16* Bt = j.Bt;
  const float* bias = j.bias;
  const int boff = j.boff;
  bf16* Cg = j.out;

  __shared__ __attribute__((aligned(16))) short ldsS[65536];  // 128 KiB

  const int tid = threadIdx.x;
  const int w = tid >> 6, l = tid & 63;
  const int l16 = l & 15, quad = l >> 4;
  const int wr = w >> 2, wc = w & 3;

  const size_t rm0 = (size_t)blockIdx.x * 256;
  const size_t cn0 = (size_t)blockIdx.y * 256;

  const int colS = ((l & 7) ^ (l >> 3)) * 8;       // shorts
  const int rowS = w * 16 + (l >> 3);              // + g*8 + h*128
  const short* pAs = (const short*)A + (rm0 + rowS) * (size_t)K + colS;
  const short* pBs = (const short*)Bt + (cn0 + rowS) * (size_t)K + colS;

  const int u0 = (quad ^ (l16 & 7)) * 8;
  const int u1 = ((quad + 4) ^ (l16 & 7)) * 8;

  f32x4 acc[8][4];
#pragma unroll
  for (int i = 0; i < 8; ++i)
#pragma unroll
    for (int j2i = 0; j2i < 4; ++j2i) acc[i][j2i] = (f32x4){0.f, 0.f, 0.f, 0.f};

  s16x8 af[4][2], bf0[2][2], bf1[2][2];

  const int T = K >> 6;  // K-tiles of 64

#ifdef HAVE_GLL
#define SA(BUF, H, KB) do {                                                          \
    __builtin_amdgcn_global_load_lds(AS1(pAs + (size_t)((H) * 128) * K + (KB)),      \
        AS3(ldsS + (BUF) * 32768 + (H) * 8192 + w * 1024), 16, 0, 0);                \
    __builtin_amdgcn_global_load_lds(AS1(pAs + (size_t)((H) * 128 + 8) * K + (KB)),  \
        AS3(ldsS + (BUF) * 32768 + (H) * 8192 + w * 1024 + 512), 16, 0, 0);          \
  } while (0)
#define SB(BUF, H, KB) do {                                                          \
    __builtin_amdgcn_global_load_lds(AS1(pBs + (size_t)((H) * 128) * K + (KB)),      \
        AS3(ldsS + (BUF) * 32768 + 16384 + (H) * 8192 + w * 1024), 16, 0, 0);        \
    __builtin_amdgcn_global_load_lds(AS1(pBs + (size_t)((H) * 128 + 8) * K + (KB)),  \
        AS3(ldsS + (BUF) * 32768 + 16384 + (H) * 8192 + w * 1024 + 512), 16, 0, 0);  \
  } while (0)
#else
#define SA(BUF, H, KB) do {                                                          \
    *(s16x8*)(ldsS + (BUF) * 32768 + (H) * 8192 + w * 1024 + l * 8) =                \
        *(const s16x8*)(pAs + (size_t)((H) * 128) * K + (KB));                       \
    *(s16x8*)(ldsS + (BUF) * 32768 + (H) * 8192 + w * 1024 + 512 + l * 8) =          \
        *(const s16x8*)(pAs + (size_t)((H) * 128 + 8) * K + (KB));                   \
  } while (0)
#define SB(BUF, H, KB) do {                                                          \
    *(s16x8*)(ldsS + (BUF) * 32768 + 16384 + (H) * 8192 + w * 1024 + l * 8) =        \
        *(const s16x8*)(pBs + (size_t)((H) * 128) * K + (KB));                       \
    *(s16x8*)(ldsS + (BUF) * 32768 + 16384 + (H) * 8192 + w * 1024 + 512 + l * 8) =  \
        *(const s16x8*)(pBs + (size_t)((H) * 128 + 8) * K + (KB));                   \
  } while (0)
#endif

#define LDA(BUF, MH) do {                                                            \
    _Pragma("unroll") for (int i = 0; i < 4; ++i) {                                  \
      const short* bse = ldsS + (BUF) * 32768 + wr * 8192 + (MH) * 4096 +            \
                         i * 1024 + l16 * 64;                                        \
      af[i][0] = *(const s16x8*)(bse + u0);                                          \
      af[i][1] = *(const s16x8*)(bse + u1);                                          \
    }                                                                                \
  } while (0)

#define LDB(BUF, NH, DST) do {                                                       \
    _Pragma("unroll") for (int n = 0; n < 2; ++n) {                                  \
      const short* bse = ldsS + (BUF) * 32768 + 16384 + (wc >> 1) * 8192 +           \
                         (wc & 1) * 4096 + (NH) * 2048 + n * 1024 + l16 * 64;        \
      DST[n][0] = *(const s16x8*)(bse + u0);                                         \
      DST[n][1] = *(const s16x8*)(bse + u1);                                         \
    }                                                                                \
  } while (0)

#define MFMAQ(MH, NH, BSET) do {                                                     \
    _Pragma("unroll") for (int i = 0; i < 4; ++i)                                    \
      _Pragma("unroll") for (int n = 0; n < 2; ++n) {                                \
        acc[(MH) * 4 + i][(NH) * 2 + n] = __builtin_amdgcn_mfma_f32_16x16x32_bf16(   \
            af[i][0], BSET[n][0], acc[(MH) * 4 + i][(NH) * 2 + n], 0, 0, 0);         \
        acc[(MH) * 4 + i][(NH) * 2 + n] = __builtin_amdgcn_mfma_f32_16x16x32_bf16(   \
            af[i][1], BSET[n][1], acc[(MH) * 4 + i][(NH) * 2 + n], 0, 0, 0);         \
      }                                                                              \
  } while (0)

#define BARX() asm volatile("s_barrier" ::: "memory")
#define LGKM0() do { asm volatile("s_waitcnt lgkmcnt(0)" ::: "memory");              \
                     __builtin_amdgcn_sched_barrier(0); } while (0)
#define VM6() do { asm volatile("s_waitcnt vmcnt(6)" ::: "memory");                  \
                   __builtin_amdgcn_sched_barrier(0); } while (0)

#define TILE_STEP(BUF, t) do {                                                       \
    const int kN_ = ((t) + 1 < T ? (t) + 1 : T - 1) << 6;                            \
    const int k2_ = ((t) + 2 < T ? (t) + 2 : T - 1) << 6;                            \
    /* ph0: all A(mh0) + all B reads; stage next tile's Ah1 (other buf) */           \
    LDA(BUF, 0); LDB(BUF, 0, bf0); LDB(BUF, 1, bf1);                                 \
    SA((BUF) ^ 1, 1, kN_);                                                           \
    BARX(); LGKM0();                                                                 \
    __builtin_amdgcn_s_setprio(1); MFMAQ(0, 0, bf0); __builtin_amdgcn_s_setprio(0);  \
    BARX();                                                                          \
    /* ph1: B slots of this buf are read-done -> stage t+2 Bh0 */                    \
    SB(BUF, 0, k2_);                                                                 \
    BARX();                                                                          \
    __builtin_amdgcn_s_setprio(1); MFMAQ(0, 1, bf1); __builtin_amdgcn_s_setprio(0);  \
    BARX();                                                                          \
    /* ph2: A(mh1) reads; stage t+2 Bh1 */                                           \
    LDA(BUF, 1);                                                                     \
    SB(BUF, 1, k2_);                                                                 \
    BARX(); LGKM0();                                                                 \
    __builtin_amdgcn_s_setprio(1); MFMAQ(1, 1, bf1); __builtin_amdgcn_s_setprio(0);  \
    BARX();                                                                          \
    /* ph3: A-half0 read-done -> stage t+2 Ah0; counted drain */                     \
    SA(BUF, 0, k2_);                                                                 \
    VM6();                                                                           \
    BARX();                                                                          \
    __builtin_amdgcn_s_setprio(1); MFMAQ(1, 0, bf0); __builtin_amdgcn_s_setprio(0);  \
    BARX();                                                                          \
  } while (0)

  // prologue: tile0 fully + tile1 {Bh0,Bh1,Ah0}; vmcnt(6) -> tile0 landed
  {
    const int k1_ = (T > 1 ? 1 : 0) << 6;
    SB(0, 0, 0); SB(0, 1, 0); SA(0, 0, 0); SA(0, 1, 0);
    SB(1, 0, k1_); SB(1, 1, k1_); SA(1, 0, k1_);
    VM6();
    BARX();
  }

  for (int t = 0; t < T; t += 2) {
    TILE_STEP(0, t);
    TILE_STEP(1, t + 1);
  }

  // epilogue: D row = quad*4+r, col = l16 (m89-verified layout)
#pragma unroll
  for (int jj = 0; jj < 4; ++jj) {
    size_t col = cn0 + wc * 64 + jj * 16 + l16;
    float bv = bias ? bias[boff + col] : 0.f;
#pragma unroll
    for (int i = 0; i < 8; ++i) {
      size_t rowb = rm0 + wr * 128 + i * 16 + quad * 4;
#pragma unroll
      for (int r = 0; r < 4; ++r) {
        Cg[(rowb + r) * (size_t)N + col] = __float2bfloat16(acc[i][jj][r] + bv);
      }
    }
  }
#undef SA
#undef SB
#undef LDA
#undef LDB
#undef MFMAQ
#undef BARX
#undef LGKM0
#undef VM6
#undef TILE_STEP
}

// ---------------------------------------------------------------------------
// batch_mid4: 4 batches per 256-thr block. Optionally fuses head-4 scores
// (Q4/KV4 live in global): 36 length-512 VALU dots per batch.
// Then: softmax(5x6x6) -> cat@linW+linb -> softmax -> A; h=A@xg+gb1 -> PReLU
// -> BN1 -> H(bf16). Also stores A (f32).
// ---------------------------------------------------------------------------
__global__ __launch_bounds__(256) void batch_mid4(
    const float* __restrict__ S, const bf16* __restrict__ XG,
    const bf16* __restrict__ Q4, const bf16* __restrict__ KV4, int fuse5,
    const float* __restrict__ linW, const float* __restrict__ linb,
    const float* __restrict__ gb1, const float* __restrict__ prelu,
    const float* __restrict__ g1, const float* __restrict__ b1,
    const float* __restrict__ m1, const float* __restrict__ v1,
    float* __restrict__ Afull, bf16* __restrict__ H) {
  const int tid = threadIdx.x, g = tid >> 6, t = tid & 63;
  const int b = blockIdx.x * 4 + g;
  __shared__ float p[4][5][6][6];
  __shared__ float Ar[4][6][6];
  __shared__ float lw[30][6];
  __shared__ float lbv[6], sc1[6], sm1[6], sb1[6];

  if (tid < 30) {
#pragma unroll
    for (int j = 0; j < 6; ++j) lw[tid][j] = linW[tid * 6 + j];
  }
  if (tid < 6) {
    lbv[tid] = linb[tid];
    sc1[tid] = g1[tid] * rsqrtf(v1[tid] + 1e-5f);
    sm1[tid] = m1[tid];
    sb1[tid] = b1[tid];
  }
  if (fuse5 && t < 36) {  // head-4 raw scores into p[g][4]
    int c = t / 6, d = t % 6;
    const s16x8* qr = (const s16x8*)((const short*)Q4 + ((size_t)b * 6 + c) * 512);
    const s16x8* kr = (const s16x8*)((const short*)KV4 + ((size_t)b * 6 + d) * 512);
    float acc = 0.f;
#pragma unroll 4
    for (int i = 0; i < 64; ++i) {
      s16x8 qa = qr[i], kb = kr[i];
#pragma unroll
      for (int j = 0; j < 8; ++j) acc += s2f(qa[j]) * s2f(kb[j]);
    }
    p[g][4][c][d] = acc;
  }
  __syncthreads();

  if (t < 30) {  // per (k,c): softmax over d
    int k = t / 6, c = t % 6;
    float v[6];
    if (k == 4 && fuse5) {
#pragma unroll
      for (int d = 0; d < 6; ++d) v[d] = p[g][4][c][d];
    } else {
      const float* sp = S + ((size_t)b * 5 + k) * 36 + c * 6;
#pragma unroll
      for (int d = 0; d < 6; ++d) v[d] = sp[d];
    }
    float mx = v[0];
#pragma unroll
    for (int d = 1; d < 6; ++d) mx = fmaxf(mx, v[d]);
    float s = 0.f;
#pragma unroll
    for (int d = 0; d < 6; ++d) { v[d] = expf(v[d] - mx); s += v[d]; }
    float inv = 1.f / s;
#pragma unroll
    for (int d = 0; d < 6; ++d) p[g][k][c][d] = v[d] * inv;
  }
  __syncthreads();

  if (t < 6) {
    int c = t;
    float ap[6];
#pragma unroll
    for (int j = 0; j < 6; ++j) ap[j] = lbv[j];
    for (int k = 0; k < 5; ++k)
#pragma unroll
      for (int d = 0; d < 6; ++d) {
        float pv = p[g][k][c][d];
#pragma unroll
        for (int j = 0; j < 6; ++j) ap[j] += pv * lw[k * 6 + d][j];
      }
    float mx = ap[0];
#pragma unroll
    for (int j = 1; j < 6; ++j) mx = fmaxf(mx, ap[j]);
    float s = 0.f;
#pragma unroll
    for (int j = 0; j < 6; ++j) { ap[j] = expf(ap[j] - mx); s += ap[j]; }
    float inv = 1.f / s;
#pragma unroll
    for (int j = 0; j < 6; ++j) {
      float a = ap[j] * inv;
      Ar[g][c][j] = a;
      Afull[(size_t)b * 36 + c * 6 + j] = a;
    }
  }
  __syncthreads();

  float pa = prelu[0];
  for (int col = t; col < 512; col += 64) {
    float xg[6];
#pragma unroll
    for (int d = 0; d < 6; ++d) xg[d] = s2f(((const short*)XG)[((size_t)b * 6 + d) * 512 + col]);
    float gbv = gb1[col];
#pragma unroll
    for (int c = 0; c < 6; ++c) {
      float h = gbv;
#pragma unroll
      for (int d = 0; d < 6; ++d) h += Ar[g][c][d] * xg[d];
      h = (h >= 0.f) ? h : pa * h;
      h = (h - sm1[c]) * sc1[c] + sb1[c];
      H[((size_t)b * 6 + c) * 512 + col] = __float2bfloat16(h);
    }
  }
}

// ---------------------------------------------------------------------------
// batch_out4: 4 batches per 256-thr block. out(f32) = BN2(A @ hw + gb2)
// ---------------------------------------------------------------------------
__global__ __launch_bounds__(256) void batch_out4(
    const float* __restrict__ Afull, const bf16* __restrict__ HW,
    const float* __restrict__ gb2,
    const float* __restrict__ g2, const float* __restrict__ b2,
    const float* __restrict__ m2, const float* __restrict__ v2,
    float* __restrict__ out) {
  const int tid = threadIdx.x, g = tid >> 6, t = tid & 63;
  const int b = blockIdx.x * 4 + g;
  __shared__ float Ar[4][36];
  __shared__ float sc[6], sm[6], sb[6];
  if (t < 36) Ar[g][t] = Afull[(size_t)b * 36 + t];
  if (tid < 6) {
    sc[tid] = g2[tid] * rsqrtf(v2[tid] + 1e-5f);
    sm[tid] = m2[tid];
    sb[tid] = b2[tid];
  }
  __syncthreads();
  for (int col = t; col < 256; col += 64) {
    float hw[6];
#pragma unroll
    for (int d = 0; d < 6; ++d) hw[d] = s2f(((const short*)HW)[((size_t)b * 6 + d) * 256 + col]);
    float gv = gb2[col];
#pragma unroll
    for (int c = 0; c < 6; ++c) {
      float o = gv;
#pragma unroll
      for (int d = 0; d < 6; ++d) o += Ar[g][c * 6 + d] * hw[d];
      o = (o - sm[c]) * sc[c] + sb[c];
      out[((size_t)b * 6 + c) * 256 + col] = o;
    }
  }
}

// ---------------------------------------------------------------------------
extern "C" void kernel_launch(void* const* d_in, const int* in_sizes, int n_in,
                              void* d_out, int out_size, void* d_ws, size_t ws_size,
                              hipStream_t stream) {
  const float* x    = (const float*)d_in[0];
  const float* aW1  = (const float*)d_in[1];
  const float* ab1  = (const float*)d_in[2];
  const float* aW2  = (const float*)d_in[3];
  const float* ab2  = (const float*)d_in[4];
  const float* linW = (const float*)d_in[5];
  const float* linb = (const float*)d_in[6];
  const float* gW1  = (const float*)d_in[7];
  const float* gb1  = (const float*)d_in[8];
  const float* gW2  = (const float*)d_in[9];
  const float* gb2  = (const float*)d_in[10];
  const float* prelu = (const float*)d_in[11];
  const float* bn1g = (const float*)d_in[12];
  const float* bn1b = (const float*)d_in[13];
  const float* bn1m = (const float*)d_in[14];
  const float* bn1v = (const float*)d_in[15];
  const float* bn2g = (const float*)d_in[16];
  const float* bn2b = (const float*)d_in[17];
  const float* bn2m = (const float*)d_in[18];
  const float* bn2v = (const float*)d_in[19];

  char* ws = (char*)d_ws;
  bf16* W1T   = (bf16*)(ws + 0);          // 5 x 512 x 1024
  bf16* W2T   = (bf16*)(ws + 5242880);    // 5 x 512 x 1024
  bf16* G1T   = (bf16*)(ws + 10485760);   // 512 x 1024
  bf16* G2T   = (bf16*)(ws + 11534336);   // 256 x 512
  float* S    = (float*)(ws + 11796480);  // 4096 x 5 x 36
  float* Af   = (float*)(ws + 14745600);  // 4096 x 36
  bf16* BufA  = (bf16*)(ws + 15335424);   // 24576x512: Q0 / Q4
  bf16* BufB  = (bf16*)(ws + 40501248);   // 24576x512: KV0 / KV4
  bf16* Xb    = (bf16*)(ws + 65667072);   // 24576x1024
  bf16* BufA2 = (bf16*)(ws + 115998720);  // 24576x512: Q1 / XG
  bf16* BufB2 = (bf16*)(ws + 141164544);  // 24576x512: KV1 / H
  bf16* BufA3 = (bf16*)(ws + 166330368);  // 24576x512: Q2   (big3)
  bf16* BufB3 = (bf16*)(ws + 191496192);  // 24576x512: KV2  (big3)
  bf16* BufA4 = (bf16*)(ws + 216662016);  // 24576x512: Q3   (big3)
  bf16* BufB4 = (bf16*)(ws + 241827840);  // 24576x512: KV3  (big3)
  const bool big  = ws_size >= 115998720ull;
  const bool big2 = ws_size >= 166330368ull;
  const bool big3 = ws_size >= 266993664ull;

  prep_kernel<<<18048, 256, 0, stream>>>(x, Xb, big ? 1 : 0,
                                         aW1, W1T, aW2, W2T, gW1, G1T, gW2, G2T);

  ScJob scz{nullptr, nullptr, nullptr, 0};

  if (big3) {
    // d1: pair {0,1} -> sets 1,2 (768 blocks = 3 full rounds)
    GJob q0{W1T, ab1, 0, BufA},                 k0{W2T, ab2, 0, BufB};
    GJob q1{W1T + 524288, ab1, 512, BufA2},     k1{W2T + 524288, ab2, 512, BufB2};
    gemm256_8ph<<<dim3(96, 2, 4), 512, 0, stream>>>(
        Xb, q0, k0, q1, k1, 4, scz, scz, 24576, 512, 1024);
    // d2: pair {2,3} -> sets 3,4 + embedded scores for pair {0,1}
    GJob q2{W1T + 2 * 524288, ab1, 1024, BufA3}, k2{W2T + 2 * 524288, ab2, 1024, BufB3};
    GJob q3{W1T + 3 * 524288, ab1, 1536, BufA4}, k3{W2T + 3 * 524288, ab2, 1536, BufB4};
    ScJob sA{BufA, BufB, S, 0}, sB{BufA2, BufB2, S, 1};
    gemm256_8ph<<<dim3(96, 2, 6), 512, 0, stream>>>(
        Xb, q2, k2, q3, k3, 4, sA, sB, 24576, 512, 1024);
    // d3: {Q4, KV4, XG} + embedded scores for pair {2,3} (rides the idle tail)
    GJob q4{W1T + 4 * 524288, ab1, 2048, BufA}, k4{W2T + 4 * 524288, ab2, 2048, BufB};
    GJob jxg{G1T, nullptr, 0, BufA2};
    ScJob sC{BufA3, BufB3, S, 2}, sD{BufA4, BufB4, S, 3};
    gemm256_8ph<<<dim3(96, 2, 5), 512, 0, stream>>>(
        Xb, q4, k4, jxg, jxg, 3, sC, sD, 24576, 512, 1024);
    // mid: head-4 scores fused (Q4=BufA, KV4=BufB); XG=BufA2; H -> BufB2
    batch_mid4<<<1024, 256, 0, stream>>>(S, BufA2, BufA, BufB, 1, linW, linb,
                                         gb1, prelu, bn1g, bn1b, bn1m, bn1v,
                                         Af, BufB2);
  } else if (big2) {
    for (int k = 0; k < 4; k += 2) {
      GJob qa{W1T + (size_t)k * 524288, ab1, k * 512, BufA};
      GJob ka{W2T + (size_t)k * 524288, ab2, k * 512, BufB};
      GJob qb{W1T + (size_t)(k + 1) * 524288, ab1, (k + 1) * 512, BufA2};
      GJob kb{W2T + (size_t)(k + 1) * 524288, ab2, (k + 1) * 512, BufB2};
      gemm256_8ph<<<dim3(96, 2, 4), 512, 0, stream>>>(
          Xb, qa, ka, qb, kb, 4, scz, scz, 24576, 512, 1024);
      scores_mfma2<<<dim3(512, 2), 256, 0, stream>>>(BufA, BufB, BufA2, BufB2, S, k);
    }
    GJob q4{W1T + 4 * 524288, ab1, 2048, BufA}, k4{W2T + 4 * 524288, ab2, 2048, BufB};
    GJob jxg{G1T, nullptr, 0, BufA2};
    gemm256_8ph<<<dim3(96, 2, 3), 512, 0, stream>>>(
        Xb, q4, k4, jxg, jxg, 4, scz, scz, 24576, 512, 1024);
    batch_mid4<<<1024, 256, 0, stream>>>(S, BufA2, BufA, BufB, 1, linW, linb,
                                         gb1, prelu, bn1g, bn1b, bn1m, bn1v,
                                         Af, BufB2);
  } else if (big) {
    for (int k = 0; k < 5; ++k) {
      GJob q{W1T + (size_t)k * 524288, ab1, k * 512, BufA};
      GJob kk{W2T + (size_t)k * 524288, ab2, k * 512, BufB};
      gemm256_8ph<<<dim3(96, 2, 2), 512, 0, stream>>>(
          Xb, q, kk, q, kk, 4, scz, scz, 24576, 512, 1024);
      scores_mfma2<<<dim3(512, 1), 256, 0, stream>>>(BufA, BufB, BufA, BufB, S, k);
    }
    GJob jxg{G1T, nullptr, 0, BufA};
    gemm256_8ph<<<dim3(96, 2, 1), 512, 0, stream>>>(
        Xb, jxg, jxg, jxg, jxg, 4, scz, scz, 24576, 512, 1024);
    batch_mid4<<<1024, 256, 0, stream>>>(S, BufA, BufA, BufA, 0, linW, linb,
                                         gb1, prelu, bn1g, bn1b, bn1m, bn1v,
                                         Af, BufB);
  } else {
    for (int k = 0; k < 5; ++k) {
      const bf16* w1 = W1T + (size_t)k * 524288;
      const bf16* w2 = W2T + (size_t)k * 524288;
      gemm_bt<1><<<dim3(192, 4, 2), 256, 0, stream>>>(
          x, w1, w2, ab1, ab2, k * 512, BufA, BufB, 24576, 512, 1024);
      scores_mfma2<<<dim3(512, 1), 256, 0, stream>>>(BufA, BufB, BufA, BufB, S, k);
    }
    gemm_bt<1><<<dim3(192, 4, 1), 256, 0, stream>>>(
        x, G1T, G1T, nullptr, nullptr, 0, BufA, BufA, 24576, 512, 1024);
    batch_mid4<<<1024, 256, 0, stream>>>(S, BufA, BufA, BufA, 0, linW, linb,
                                         gb1, prelu, bn1g, bn1b, bn1m, bn1v,
                                         Af, BufB);
  }

  // HW = H @ gW2 -> BufA (legacy 128^2: (192,2)=384 blocks, good fill at N=256)
  bf16* Hbuf = big2 ? BufB2 : BufB;
  gemm_bt<0><<<dim3(192, 2, 1), 256, 0, stream>>>(
      Hbuf, G2T, G2T, nullptr, nullptr, 0, BufA, BufA, 24576, 256, 512);

  batch_out4<<<1024, 256, 0, stream>>>(Af, BufA, gb2, bn2g, bn2b, bn2m, bn2v,
                                       (float*)d_out);
}

// Round 4
// 629.903 us; speedup vs baseline: 1.0106x; 1.0106x over previous
//
#include <hip/hip_runtime.h>
#include <hip/hip_bf16.h>

// MHAGCN: x(4096,6,1024) f32 -> out(4096,6,256) f32. Internal bf16 + MFMA.
// R10: structural consolidation.
//  - h = A@(x@gW1) re-associated to (A@x)@gW1: mid computes Xa=A@x IN-PLACE
//    into Xb (block-private rows), then H' = Xa@gW1 with fused
//    bias+PReLU+BN1 epilogue. XG panel and its GEMM slice are gone.
//  - all 5 heads' scores computed inside mid as per-wave MFMAs (packing =
//    verified scores_wave structure, heads instead of batch-pairs). No
//    standalone scores launches, no S round-trip (big path).
//  - ONE 10-slice Q/KV dispatch (96,2,10)=1920 blocks=7.5 rounds (Q4 panel
//    -> d_out (exactly 25 MB, dead until out4), KV4 -> P8; needs ws>=292 MB,
//    else proven-267MB fallback: pair dispatches + standalone scores).
//  - gemm256_8ph epilogue: stage wave's 128x64 bf16 tile in its private
//    16KB LDS, store coalesced 16B/lane (was 2-byte scalar stores, ~2x HBM
//    write amplification in R9 counters).
// R9 lesson: light z-slices inherit 128KiB LDS -> 1 block/CU -> serial tail
// rounds; embedding removed.

using bf16 = __hip_bfloat16;
using s16x8 = __attribute__((ext_vector_type(8))) short;
using f32x4 = __attribute__((ext_vector_type(4))) float;

#define AS1(p) ((__attribute__((address_space(1))) void*)((void*)(p)))
#define AS3(p) ((__attribute__((address_space(3))) void*)(p))

#if defined(__has_builtin)
#if __has_builtin(__builtin_amdgcn_global_load_lds)
#define HAVE_GLL 1
#endif
#endif

__device__ __forceinline__ float s2f(short s) {
  union { unsigned int u; float f; } c;
  c.u = ((unsigned int)(unsigned short)s) << 16;
  return c.f;
}
__device__ __forceinline__ short f2s(float x) {
  bf16 b = __float2bfloat16(x);
  short s;
  __builtin_memcpy(&s, &b, 2);
  return s;
}

// GEMM output-routing job (selected per blockIdx.z)
struct GJob {
  const bf16* Bt;
  const float* bias;
  int boff;
  bf16* out;
};
struct GJobs10 {
  GJob j[10];
};

// ---------------------------------------------------------------------------
// prep: cvt x->bf16 (blocks [0,12288)) + 4 weight transposes ([12288,18048))
// ---------------------------------------------------------------------------
__global__ __launch_bounds__(256) void prep_kernel(
    const float* __restrict__ x, bf16* __restrict__ Xb,
    const float* __restrict__ aW1, bf16* __restrict__ W1T,
    const float* __restrict__ aW2, bf16* __restrict__ W2T,
    const float* __restrict__ gW1, bf16* __restrict__ G1T,
    const float* __restrict__ gW2, bf16* __restrict__ G2T) {
  const int bid = blockIdx.x, tid = threadIdx.x;
  if (bid < 12288) {
    int i = bid * 256 + tid;  // < 3145728
    float4 p0 = ((const float4*)x)[i * 2];
    float4 p1 = ((const float4*)x)[i * 2 + 1];
    s16x8 v;
    v[0] = f2s(p0.x); v[1] = f2s(p0.y); v[2] = f2s(p0.z); v[3] = f2s(p0.w);
    v[4] = f2s(p1.x); v[5] = f2s(p1.y); v[6] = f2s(p1.z); v[7] = f2s(p1.w);
    ((s16x8*)Xb)[i] = v;
    return;
  }
  int r = bid - 12288;
  const float* src; short* dst; int R, C, bx, by;
  if (r < 2560) {
    int z = r >> 9, q = r & 511;
    src = aW1 + (size_t)z * 524288; dst = (short*)W1T + (size_t)z * 524288;
    R = 1024; C = 512; bx = q & 31; by = q >> 5;
  } else if (r < 5120) {
    r -= 2560;
    int z = r >> 9, q = r & 511;
    src = aW2 + (size_t)z * 524288; dst = (short*)W2T + (size_t)z * 524288;
    R = 1024; C = 512; bx = q & 31; by = q >> 5;
  } else if (r < 5632) {
    r -= 5120;
    src = gW1; dst = (short*)G1T; R = 1024; C = 512; bx = r & 31; by = r >> 5;
  } else {
    r -= 5632;
    src = gW2; dst = (short*)G2T; R = 512; C = 256; bx = r & 15; by = r >> 4;
  }
  __shared__ short tile[32][33];
  const int tx = tid & 31, ty = tid >> 5;  // (32, 8)
  const int r0 = bx * 32, c0 = by * 32;
#pragma unroll
  for (int i = 0; i < 4; ++i)
    tile[ty + i * 8][tx] = f2s(src[(size_t)(r0 + ty + i * 8) * C + c0 + tx]);
  __syncthreads();
#pragma unroll
  for (int i = 0; i < 4; ++i)
    dst[(size_t)(c0 + ty + i * 8) * R + r0 + tx] = tile[tx][ty + i * 8];
}

// ---------------------------------------------------------------------------
// scores wave body (verified packing): rows {A: 0-7, B: 8-15} on BOTH m,n;
// valid outputs are the diagonal blocks. Generic over the two (Q,KV) sources
// and destinations so it serves batch-pairs (standalone) and head-pairs (mid).
// ---------------------------------------------------------------------------
__device__ __forceinline__ void scores_grp(
    const bf16* __restrict__ Qa, const bf16* __restrict__ Ka,
    const bf16* __restrict__ Qb, const bf16* __restrict__ Kb,
    int rowA, int rowB,            // global base row (x6 already applied)
    float* __restrict__ dstA, float* __restrict__ dstB,  // 6x6 each
    int lane) {
  const int l16 = lane & 15, quad = lane >> 4;
  int lr = l16 & 7; if (lr > 5) lr = 5;
  const int gr = ((l16 < 8) ? rowA : rowB) + lr;
  const short* qrow = (const short*)((l16 < 8) ? Qa : Qb) + (size_t)gr * 512 + quad * 8;
  const short* krow = (const short*)((l16 < 8) ? Ka : Kb) + (size_t)gr * 512 + quad * 8;

  f32x4 acc = (f32x4){0.f, 0.f, 0.f, 0.f};
#pragma unroll
  for (int kk = 0; kk < 16; ++kk) {
    s16x8 a = *(const s16x8*)(qrow + kk * 32);
    s16x8 b = *(const s16x8*)(krow + kk * 32);
    acc = __builtin_amdgcn_mfma_f32_16x16x32_bf16(a, b, acc, 0, 0, 0);
  }

  if (l16 < 6) {
#pragma unroll
    for (int r = 0; r < 4; ++r) {
      int m = quad * 4 + r;
      if (m < 6) dstA[m * 6 + l16] = acc[r];
    }
  } else if (l16 >= 8 && l16 < 14) {
#pragma unroll
    for (int r = 0; r < 4; ++r) {
      int m = quad * 4 + r;
      if (m >= 8 && m < 14) dstB[(m - 8) * 6 + (l16 - 8)] = acc[r];
    }
  }
}

// standalone scores (fallback path); up to 2 heads via blockIdx.y; per wave:
// 2 batches (rowA=b0*6, rowB=(b0+1)*6), writes straight to S.
__global__ __launch_bounds__(256) void scores_mfma2(
    const bf16* __restrict__ Q0, const bf16* __restrict__ KV0,
    const bf16* __restrict__ Q1, const bf16* __restrict__ KV1,
    float* __restrict__ S, int head0) {
  const int h = blockIdx.y;
  const bf16* Q = h ? Q1 : Q0;
  const bf16* KV = h ? KV1 : KV0;
  const int head = head0 + h;
  const int lane = threadIdx.x & 63, w = threadIdx.x >> 6;
  const int b0 = (blockIdx.x * 4 + w) * 2;
  scores_grp(Q, KV, Q, KV, b0 * 6, (b0 + 1) * 6,
             S + ((size_t)b0 * 5 + head) * 36,
             S + ((size_t)(b0 + 1) * 5 + head) * 36, lane);
}

// ---------------------------------------------------------------------------
// Legacy 128x128 GEMM (m97 structure) — used for the HW gemm (N=256:
// (192,2)=384 light blocks beat 96 blocks of 256^2).
// ---------------------------------------------------------------------------
template <int AF32>
__global__ __launch_bounds__(256) void gemm_bt(
    const void* __restrict__ Ag,
    const bf16* __restrict__ Bt0, const bf16* __restrict__ Bt1,
    const float* __restrict__ bias0, const float* __restrict__ bias1, int boff,
    bf16* __restrict__ out0, bf16* __restrict__ out1,
    int M, int N, int K) {
  const bf16* Bt = (blockIdx.z == 0) ? Bt0 : Bt1;
  const float* bias = (blockIdx.z == 0) ? bias0 : bias1;
  bf16* Cg = (blockIdx.z == 0) ? out0 : out1;

  __shared__ short lA[128 * 32];
  __shared__ short lB[128 * 32];

  const int tid = threadIdx.x;
  const int lane = tid & 63, w = tid >> 6;
  const int wr = w >> 1, wc = w & 1;
  const int l16 = lane & 15, quad = lane >> 4;
  const int lrow = lane >> 2;
  const int scol = (((lane & 3) ^ ((lane >> 3) & 3)) * 8);

  const size_t rm0 = (size_t)blockIdx.x * 128;
  const size_t cn0 = (size_t)blockIdx.y * 128;

  f32x4 acc[4][4];
#pragma unroll
  for (int i = 0; i < 4; ++i)
#pragma unroll
    for (int j = 0; j < 4; ++j) acc[i][j] = (f32x4){0.f, 0.f, 0.f, 0.f};

  for (int kb = 0; kb < K; kb += 32) {
#pragma unroll
    for (int t = 0; t < 2; ++t) {
      int chunk = w * 2 + t;
      int row = chunk * 16 + lrow;
      const bf16* gb = Bt + (cn0 + row) * (size_t)K + kb + scol;
#ifdef HAVE_GLL
      __builtin_amdgcn_global_load_lds(AS1(gb), AS3(lB + chunk * 512), 16, 0, 0);
#else
      *(s16x8*)(lB + chunk * 512 + lane * 8) = *(const s16x8*)gb;
#endif
      if (AF32) {
        const float* ga = (const float*)Ag + (rm0 + row) * (size_t)K + kb + scol;
        float4 p0 = *(const float4*)ga;
        float4 p1 = *(const float4*)(ga + 4);
        s16x8 v;
        v[0] = f2s(p0.x); v[1] = f2s(p0.y); v[2] = f2s(p0.z); v[3] = f2s(p0.w);
        v[4] = f2s(p1.x); v[5] = f2s(p1.y); v[6] = f2s(p1.z); v[7] = f2s(p1.w);
        *(s16x8*)(lA + chunk * 512 + lane * 8) = v;
      } else {
        const bf16* ga = (const bf16*)Ag + (rm0 + row) * (size_t)K + kb + scol;
#ifdef HAVE_GLL
        __builtin_amdgcn_global_load_lds(AS1(ga), AS3(lA + chunk * 512), 16, 0, 0);
#else
        *(s16x8*)(lA + chunk * 512 + lane * 8) = *(const s16x8*)ga;
#endif
      }
    }
    __syncthreads();

    const int q2 = (quad ^ ((l16 >> 1) & 3)) * 8;
    s16x8 af[4], bfv[4];
#pragma unroll
    for (int i = 0; i < 4; ++i) {
      af[i] = *(const s16x8*)(lA + (wr * 64 + i * 16 + l16) * 32 + q2);
      bfv[i] = *(const s16x8*)(lB + (wc * 64 + i * 16 + l16) * 32 + q2);
    }
#pragma unroll
    for (int i = 0; i < 4; ++i)
#pragma unroll
      for (int j = 0; j < 4; ++j)
        acc[i][j] = __builtin_amdgcn_mfma_f32_16x16x32_bf16(af[i], bfv[j], acc[i][j], 0, 0, 0);
    __syncthreads();
  }

#pragma unroll
  for (int j = 0; j < 4; ++j) {
    size_t col = cn0 + wc * 64 + j * 16 + l16;
    float bv = bias ? bias[boff + col] : 0.f;
#pragma unroll
    for (int i = 0; i < 4; ++i) {
      size_t rowb = rm0 + wr * 64 + i * 16 + quad * 4;
#pragma unroll
      for (int r = 0; r < 4; ++r) {
        float v = acc[i][j][r] + bv;
        Cg[(rowb + r) * (size_t)N + col] = __float2bfloat16(v);
      }
    }
  }
}

// ---------------------------------------------------------------------------
// 256x256 8-phase GEMM (m201 template). Inner loop identical to R7-R9
// (verified). New: per-z GJob array (up to 10 slices), optional fused
// bias+PReLU+BN1 epilogue (epi_z selects the slice), and LDS-staged
// coalesced output stores (wave-private 16KB region, after final barrier).
// ---------------------------------------------------------------------------
__global__ __launch_bounds__(512, 2) void gemm256_8ph(
    const bf16* __restrict__ A, GJobs10 jobs, int epi_z,
    const float* __restrict__ prelu_p,
    const float* __restrict__ bn_g, const float* __restrict__ bn_b,
    const float* __restrict__ bn_m, const float* __restrict__ bn_v,
    int M, int N, int K) {
  const GJob jb = jobs.j[blockIdx.z];
  const bf16* Bt = jb.Bt;
  const float* bias = jb.bias;
  const int boff = jb.boff;
  bf16* Cg = jb.out;
  const bool EPI = (epi_z == (int)blockIdx.z);

  __shared__ __attribute__((aligned(16))) short ldsS[65536];  // 128 KiB
  __shared__ float epi_s[12];

  const int tid = threadIdx.x;
  const int w = tid >> 6, l = tid & 63;
  const int l16 = l & 15, quad = l >> 4;
  const int wr = w >> 2, wc = w & 3;

  if (EPI && tid < 6) {
    float s = bn_g[tid] * rsqrtf(bn_v[tid] + 1e-5f);
    epi_s[tid] = s;
    epi_s[6 + tid] = bn_b[tid] - bn_m[tid] * s;
  }

  const size_t rm0 = (size_t)blockIdx.x * 256;
  const size_t cn0 = (size_t)blockIdx.y * 256;

  const int colS = ((l & 7) ^ (l >> 3)) * 8;       // shorts
  const int rowS = w * 16 + (l >> 3);              // + g*8 + h*128
  const short* pAs = (const short*)A + (rm0 + rowS) * (size_t)K + colS;
  const short* pBs = (const short*)Bt + (cn0 + rowS) * (size_t)K + colS;

  const int u0 = (quad ^ (l16 & 7)) * 8;
  const int u1 = ((quad + 4) ^ (l16 & 7)) * 8;

  f32x4 acc[8][4];
#pragma unroll
  for (int i = 0; i < 8; ++i)
#pragma unroll
    for (int j2i = 0; j2i < 4; ++j2i) acc[i][j2i] = (f32x4){0.f, 0.f, 0.f, 0.f};

  s16x8 af[4][2], bf0[2][2], bf1[2][2];

  const int T = K >> 6;  // K-tiles of 64

#ifdef HAVE_GLL
#define SA(BUF, H, KB) do {                                                          \
    __builtin_amdgcn_global_load_lds(AS1(pAs + (size_t)((H) * 128) * K + (KB)),      \
        AS3(ldsS + (BUF) * 32768 + (H) * 8192 + w * 1024), 16, 0, 0);                \
    __builtin_amdgcn_global_load_lds(AS1(pAs + (size_t)((H) * 128 + 8) * K + (KB)),  \
        AS3(ldsS + (BUF) * 32768 + (H) * 8192 + w * 1024 + 512), 16, 0, 0);          \
  } while (0)
#define SB(BUF, H, KB) do {                                                          \
    __builtin_amdgcn_global_load_lds(AS1(pBs + (size_t)((H) * 128) * K + (KB)),      \
        AS3(ldsS + (BUF) * 32768 + 16384 + (H) * 8192 + w * 1024), 16, 0, 0);        \
    __builtin_amdgcn_global_load_lds(AS1(pBs + (size_t)((H) * 128 + 8) * K + (KB)),  \
        AS3(ldsS + (BUF) * 32768 + 16384 + (H) * 8192 + w * 1024 + 512), 16, 0, 0);  \
  } while (0)
#else
#define SA(BUF, H, KB) do {                                                          \
    *(s16x8*)(ldsS + (BUF) * 32768 + (H) * 8192 + w * 1024 + l * 8) =                \
        *(const s16x8*)(pAs + (size_t)((H) * 128) * K + (KB));                       \
    *(s16x8*)(ldsS + (BUF) * 32768 + (H) * 8192 + w * 1024 + 512 + l * 8) =          \
        *(const s16x8*)(pAs + (size_t)((H) * 128 + 8) * K + (KB));                   \
  } while (0)
#define SB(BUF, H, KB) do {                                                          \
    *(s16x8*)(ldsS + (BUF) * 32768 + 16384 + (H) * 8192 + w * 1024 + l * 8) =        \
        *(const s16x8*)(pBs + (size_t)((H) * 128) * K + (KB));                       \
    *(s16x8*)(ldsS + (BUF) * 32768 + 16384 + (H) * 8192 + w * 1024 + 512 + l * 8) =  \
        *(const s16x8*)(pBs + (size_t)((H) * 128 + 8) * K + (KB));                   \
  } while (0)
#endif

#define LDA(BUF, MH) do {                                                            \
    _Pragma("unroll") for (int i = 0; i < 4; ++i) {                                  \
      const short* bse = ldsS + (BUF) * 32768 + wr * 8192 + (MH) * 4096 +            \
                         i * 1024 + l16 * 64;                                        \
      af[i][0] = *(const s16x8*)(bse + u0);                                          \
      af[i][1] = *(const s16x8*)(bse + u1);                                          \
    }                                                                                \
  } while (0)

#define LDB(BUF, NH, DST) do {                                                       \
    _Pragma("unroll") for (int n = 0; n < 2; ++n) {                                  \
      const short* bse = ldsS + (BUF) * 32768 + 16384 + (wc >> 1) * 8192 +           \
                         (wc & 1) * 4096 + (NH) * 2048 + n * 1024 + l16 * 64;        \
      DST[n][0] = *(const s16x8*)(bse + u0);                                         \
      DST[n][1] = *(const s16x8*)(bse + u1);                                         \
    }                                                                                \
  } while (0)

#define MFMAQ(MH, NH, BSET) do {                                                     \
    _Pragma("unroll") for (int i = 0; i < 4; ++i)                                    \
      _Pragma("unroll") for (int n = 0; n < 2; ++n) {                                \
        acc[(MH) * 4 + i][(NH) * 2 + n] = __builtin_amdgcn_mfma_f32_16x16x32_bf16(   \
            af[i][0], BSET[n][0], acc[(MH) * 4 + i][(NH) * 2 + n], 0, 0, 0);         \
        acc[(MH) * 4 + i][(NH) * 2 + n] = __builtin_amdgcn_mfma_f32_16x16x32_bf16(   \
            af[i][1], BSET[n][1], acc[(MH) * 4 + i][(NH) * 2 + n], 0, 0, 0);         \
      }                                                                              \
  } while (0)

#define BARX() asm volatile("s_barrier" ::: "memory")
#define LGKM0() do { asm volatile("s_waitcnt lgkmcnt(0)" ::: "memory");              \
                     __builtin_amdgcn_sched_barrier(0); } while (0)
#define VM6() do { asm volatile("s_waitcnt vmcnt(6)" ::: "memory");                  \
                   __builtin_amdgcn_sched_barrier(0); } while (0)

#define TILE_STEP(BUF, t) do {                                                       \
    const int kN_ = ((t) + 1 < T ? (t) + 1 : T - 1) << 6;                            \
    const int k2_ = ((t) + 2 < T ? (t) + 2 : T - 1) << 6;                            \
    /* ph0: all A(mh0) + all B reads; stage next tile's Ah1 (other buf) */           \
    LDA(BUF, 0); LDB(BUF, 0, bf0); LDB(BUF, 1, bf1);                                 \
    SA((BUF) ^ 1, 1, kN_);                                                           \
    BARX(); LGKM0();                                                                 \
    __builtin_amdgcn_s_setprio(1); MFMAQ(0, 0, bf0); __builtin_amdgcn_s_setprio(0);  \
    BARX();                                                                          \
    /* ph1: B slots of this buf are read-done -> stage t+2 Bh0 */                    \
    SB(BUF, 0, k2_);                                                                 \
    BARX();                                                                          \
    __builtin_amdgcn_s_setprio(1); MFMAQ(0, 1, bf1); __builtin_amdgcn_s_setprio(0);  \
    BARX();                                                                          \
    /* ph2: A(mh1) reads; stage t+2 Bh1 */                                           \
    LDA(BUF, 1);                                                                     \
    SB(BUF, 1, k2_);                                                                 \
    BARX(); LGKM0();                                                                 \
    __builtin_amdgcn_s_setprio(1); MFMAQ(1, 1, bf1); __builtin_amdgcn_s_setprio(0);  \
    BARX();                                                                          \
    /* ph3: A-half0 read-done -> stage t+2 Ah0; counted drain */                     \
    SA(BUF, 0, k2_);                                                                 \
    VM6();                                                                           \
    BARX();                                                                          \
    __builtin_amdgcn_s_setprio(1); MFMAQ(1, 0, bf0); __builtin_amdgcn_s_setprio(0);  \
    BARX();                                                                          \
  } while (0)

  // prologue: tile0 fully + tile1 {Bh0,Bh1,Ah0}; vmcnt(6) -> tile0 landed
  {
    const int k1_ = (T > 1 ? 1 : 0) << 6;
    SB(0, 0, 0); SB(0, 1, 0); SA(0, 0, 0); SA(0, 1, 0);
    SB(1, 0, k1_); SB(1, 1, k1_); SA(1, 0, k1_);
    VM6();
    BARX();
  }

  for (int t = 0; t < T; t += 2) {
    TILE_STEP(0, t);
    TILE_STEP(1, t + 1);
  }

  // ---- epilogue: stage wave's 128x64 bf16 tile in private LDS, then
  // coalesced 16B/lane stores. D row = quad*4+r, col = l16 (m89-verified).
  float pa = EPI ? prelu_p[0] : 0.f;
  short* st = ldsS + w * 8192;
#pragma unroll
  for (int jj = 0; jj < 4; ++jj) {
    int coll = jj * 16 + l16;
    float bv = bias ? bias[boff + (int)cn0 + wc * 64 + coll] : 0.f;
#pragma unroll
    for (int i = 0; i < 8; ++i) {
#pragma unroll
      for (int r = 0; r < 4; ++r) {
        int rowl = i * 16 + quad * 4 + r;
        float v = acc[i][jj][r] + bv;
        if (EPI) {
          v = (v >= 0.f) ? v : pa * v;
          int c = (int)((rm0 + wr * 128 + rowl) % 6);
          v = v * epi_s[c] + epi_s[6 + c];
        }
        st[rowl * 64 + coll] = f2s(v);
      }
    }
  }
  __syncthreads();
#pragma unroll
  for (int it = 0; it < 16; ++it) {
    int rowl = it * 8 + (l >> 3);
    int cch = (l & 7) * 8;
    s16x8 vv = *(const s16x8*)(st + rowl * 64 + cch);
    *(s16x8*)((short*)Cg + (rm0 + wr * 128 + rowl) * (size_t)N +
              cn0 + wc * 64 + cch) = vv;
  }
#undef SA
#undef SB
#undef LDA
#undef LDB
#undef MFMAQ
#undef BARX
#undef LGKM0
#undef VM6
#undef TILE_STEP
}

// ---------------------------------------------------------------------------
// mid5: 4 batches per 256-thr block (wave g <-> batch b).
//  ALLP=1: scores for all 5 heads via 3 MFMA groups (head-pairs (0,1),(2,3),
//          (4,4)) reading the Q/KV panels.
//  ALLP=0: heads 0-3 from S (standalone scores), head 4 via MFMA.
// Then per-head softmax -> cat@linW+linb -> softmax -> A (stored to Afull),
// and Xa = A @ x written IN-PLACE into Xb (block-private rows).
// ---------------------------------------------------------------------------
template <int ALLP>
__global__ __launch_bounds__(256) void mid5(
    const float* __restrict__ S,
    const bf16* __restrict__ Q0, const bf16* __restrict__ Q1,
    const bf16* __restrict__ Q2, const bf16* __restrict__ Q3,
    const bf16* __restrict__ K0, const bf16* __restrict__ K1,
    const bf16* __restrict__ K2, const bf16* __restrict__ K3,
    const bf16* __restrict__ Q4, const bf16* __restrict__ K4,
    bf16* __restrict__ Xb,
    const float* __restrict__ linW, const float* __restrict__ linb,
    float* __restrict__ Afull) {
  const int tid = threadIdx.x, g = tid >> 6, t = tid & 63;
  const int b = blockIdx.x * 4 + g;
  __shared__ float p[4][5][6][6];
  __shared__ float Ar[4][6][6];
  __shared__ float lw[30][6];
  __shared__ float lbv[6];

  if (tid < 30) {
#pragma unroll
    for (int j = 0; j < 6; ++j) lw[tid][j] = linW[tid * 6 + j];
  }
  if (tid < 6) lbv[tid] = linb[tid];

  const int r6 = b * 6;
  if (ALLP) {
    scores_grp(Q0, K0, Q1, K1, r6, r6, &p[g][0][0][0], &p[g][1][0][0], t);
    scores_grp(Q2, K2, Q3, K3, r6, r6, &p[g][2][0][0], &p[g][3][0][0], t);
    scores_grp(Q4, K4, Q4, K4, r6, r6, &p[g][4][0][0], &p[g][4][0][0], t);
  } else {
    if (t < 36) {
#pragma unroll
      for (int k = 0; k < 4; ++k)
        p[g][k][t / 6][t % 6] = S[((size_t)b * 5 + k) * 36 + t];
    }
    scores_grp(Q4, K4, Q4, K4, r6, r6, &p[g][4][0][0], &p[g][4][0][0], t);
  }
  __syncthreads();

  if (t < 30) {  // per (k,c): softmax over d, in place
    int k = t / 6, c = t % 6;
    float v[6];
#pragma unroll
    for (int d = 0; d < 6; ++d) v[d] = p[g][k][c][d];
    float mx = v[0];
#pragma unroll
    for (int d = 1; d < 6; ++d) mx = fmaxf(mx, v[d]);
    float s = 0.f;
#pragma unroll
    for (int d = 0; d < 6; ++d) { v[d] = expf(v[d] - mx); s += v[d]; }
    float inv = 1.f / s;
#pragma unroll
    for (int d = 0; d < 6; ++d) p[g][k][c][d] = v[d] * inv;
  }
  __syncthreads();

  if (t < 6) {
    int c = t;
    float ap[6];
#pragma unroll
    for (int j = 0; j < 6; ++j) ap[j] = lbv[j];
    for (int k = 0; k < 5; ++k)
#pragma unroll
      for (int d = 0; d < 6; ++d) {
        float pv = p[g][k][c][d];
#pragma unroll
        for (int j = 0; j < 6; ++j) ap[j] += pv * lw[k * 6 + d][j];
      }
    float mx = ap[0];
#pragma unroll
    for (int j = 1; j < 6; ++j) mx = fmaxf(mx, ap[j]);
    float s = 0.f;
#pragma unroll
    for (int j = 0; j < 6; ++j) { ap[j] = expf(ap[j] - mx); s += ap[j]; }
    float inv = 1.f / s;
#pragma unroll
    for (int j = 0; j < 6; ++j) {
      float a = ap[j] * inv;
      Ar[g][c][j] = a;
      Afull[(size_t)b * 36 + c * 6 + j] = a;
    }
  }
  __syncthreads();

  // Xa = A @ x, in place into Xb. Thread t reads all 6 rows at its cols,
  // then writes all 6 rows at the same cols: race-free (rows block-private,
  // cols thread-private, reads precede writes within thread).
  short* xp = (short*)Xb;
#pragma unroll
  for (int it = 0; it < 2; ++it) {
    int c8 = (it * 64 + t) * 8;
    s16x8 xv[6];
#pragma unroll
    for (int d = 0; d < 6; ++d)
      xv[d] = *(const s16x8*)(xp + ((size_t)r6 + d) * 1024 + c8);
#pragma unroll
    for (int c = 0; c < 6; ++c) {
      s16x8 o;
#pragma unroll
      for (int e = 0; e < 8; ++e) {
        float s = 0.f;
#pragma unroll
        for (int d = 0; d < 6; ++d) s += Ar[g][c][d] * s2f(xv[d][e]);
        o[e] = f2s(s);
      }
      *(s16x8*)(xp + ((size_t)r6 + c) * 1024 + c8) = o;
    }
  }
}

// ---------------------------------------------------------------------------
// batch_out4: 4 batches per 256-thr block. out(f32) = BN2(A @ hw + gb2)
// ---------------------------------------------------------------------------
__global__ __launch_bounds__(256) void batch_out4(
    const float* __restrict__ Afull, const bf16* __restrict__ HW,
    const float* __restrict__ gb2,
    const float* __restrict__ g2, const float* __restrict__ b2,
    const float* __restrict__ m2, const float* __restrict__ v2,
    float* __restrict__ out) {
  const int tid = threadIdx.x, g = tid >> 6, t = tid & 63;
  const int b = blockIdx.x * 4 + g;
  __shared__ float Ar[4][36];
  __shared__ float sc[6], sm[6], sb[6];
  if (t < 36) Ar[g][t] = Afull[(size_t)b * 36 + t];
  if (tid < 6) {
    sc[tid] = g2[tid] * rsqrtf(v2[tid] + 1e-5f);
    sm[tid] = m2[tid];
    sb[tid] = b2[tid];
  }
  __syncthreads();
  for (int col = t; col < 256; col += 64) {
    float hw[6];
#pragma unroll
    for (int d = 0; d < 6; ++d) hw[d] = s2f(((const short*)HW)[((size_t)b * 6 + d) * 256 + col]);
    float gv = gb2[col];
#pragma unroll
    for (int c = 0; c < 6; ++c) {
      float o = gv;
#pragma unroll
      for (int d = 0; d < 6; ++d) o += Ar[g][c * 6 + d] * hw[d];
      o = (o - sm[c]) * sc[c] + sb[c];
      out[((size_t)b * 6 + c) * 256 + col] = o;
    }
  }
}

// ---------------------------------------------------------------------------
extern "C" void kernel_launch(void* const* d_in, const int* in_sizes, int n_in,
                              void* d_out, int out_size, void* d_ws, size_t ws_size,
                              hipStream_t stream) {
  const float* x    = (const float*)d_in[0];
  const float* aW1  = (const float*)d_in[1];
  const float* ab1  = (const float*)d_in[2];
  const float* aW2  = (const float*)d_in[3];
  const float* ab2  = (const float*)d_in[4];
  const float* linW = (const float*)d_in[5];
  const float* linb = (const float*)d_in[6];
  const float* gW1  = (const float*)d_in[7];
  const float* gb1  = (const float*)d_in[8];
  const float* gW2  = (const float*)d_in[9];
  const float* gb2  = (const float*)d_in[10];
  const float* prelu = (const float*)d_in[11];
  const float* bn1g = (const float*)d_in[12];
  const float* bn1b = (const float*)d_in[13];
  const float* bn1m = (const float*)d_in[14];
  const float* bn1v = (const float*)d_in[15];
  const float* bn2g = (const float*)d_in[16];
  const float* bn2b = (const float*)d_in[17];
  const float* bn2m = (const float*)d_in[18];
  const float* bn2v = (const float*)d_in[19];

  char* ws = (char*)d_ws;
  bf16* W1T = (bf16*)(ws + 0);           // 5 x 512 x 1024
  bf16* W2T = (bf16*)(ws + 5242880);     // 5 x 512 x 1024
  bf16* G1T = (bf16*)(ws + 10485760);    // 512 x 1024
  bf16* G2T = (bf16*)(ws + 11534336);    // 256 x 512
  float* S  = (float*)(ws + 11796480);   // 4096 x 5 x 36 (fallback only)
  float* Af = (float*)(ws + 14745600);   // 4096 x 36
  bf16* Xb  = (bf16*)(ws + 15335424);    // 24576 x 1024 (x bf16, then Xa=A@x)
#define PANEL(i) ((bf16*)(ws + 65667072 + (size_t)(i) * 25165824))  // 24576x512
  const bool big5 = ws_size >= 292159488ull;  // P8 exists
  // ws >= 266993664 (P0..P7 + Xb) proven by R9's big3 run.

  prep_kernel<<<18048, 256, 0, stream>>>(x, Xb, aW1, W1T, aW2, W2T, gW1, G1T, gW2, G2T);

  GJobs10 J{};

  if (big5) {
    // ---- ONE Q/KV dispatch: 10 slices (1920 blocks = 7.5 rounds) ----
    for (int h = 0; h < 4; ++h) {
      J.j[2 * h]     = GJob{W1T + (size_t)h * 524288, ab1, h * 512, PANEL(2 * h)};
      J.j[2 * h + 1] = GJob{W2T + (size_t)h * 524288, ab2, h * 512, PANEL(2 * h + 1)};
    }
    J.j[8] = GJob{W1T + 4 * 524288, ab1, 2048, (bf16*)d_out};  // Q4 -> d_out scratch
    J.j[9] = GJob{W2T + 4 * 524288, ab2, 2048, PANEL(8)};      // KV4
    gemm256_8ph<<<dim3(96, 2, 10), 512, 0, stream>>>(
        Xb, J, -1, nullptr, nullptr, nullptr, nullptr, nullptr, 24576, 512, 1024);

    // ---- mid: all scores (MFMA) + A + Xa in-place ----
    mid5<1><<<1024, 256, 0, stream>>>(
        nullptr, PANEL(0), PANEL(2), PANEL(4), PANEL(6),
        PANEL(1), PANEL(3), PANEL(5), PANEL(7),
        (const bf16*)d_out, PANEL(8), Xb, linW, linb, Af);

    // ---- H' = Xa @ gW1 with fused gb1 + PReLU + BN1 -> P0 ----
    GJobs10 JH{};
    JH.j[0] = GJob{G1T, gb1, 0, PANEL(0)};
    gemm256_8ph<<<dim3(96, 2, 1), 512, 0, stream>>>(
        Xb, JH, 0, prelu, bn1g, bn1b, bn1m, bn1v, 24576, 512, 1024);

    // ---- HW = H @ gW2 -> P1 ----
    gemm_bt<0><<<dim3(192, 2, 1), 256, 0, stream>>>(
        PANEL(0), G2T, G2T, nullptr, nullptr, 0, PANEL(1), PANEL(1), 24576, 256, 512);

    batch_out4<<<1024, 256, 0, stream>>>(Af, PANEL(1), gb2, bn2g, bn2b, bn2m, bn2v,
                                         (float*)d_out);
  } else {
    // ---- fallback (proven ws >= 267 MB): pairs + standalone scores ----
    for (int h = 0; h < 2; ++h) {
      J.j[2 * h]     = GJob{W1T + (size_t)h * 524288, ab1, h * 512, PANEL(2 * h)};
      J.j[2 * h + 1] = GJob{W2T + (size_t)h * 524288, ab2, h * 512, PANEL(2 * h + 1)};
    }
    gemm256_8ph<<<dim3(96, 2, 4), 512, 0, stream>>>(
        Xb, J, -1, nullptr, nullptr, nullptr, nullptr, nullptr, 24576, 512, 1024);
    scores_mfma2<<<dim3(512, 2), 256, 0, stream>>>(
        PANEL(0), PANEL(1), PANEL(2), PANEL(3), S, 0);

    for (int h = 0; h < 2; ++h) {
      J.j[2 * h]     = GJob{W1T + (size_t)(h + 2) * 524288, ab1, (h + 2) * 512, PANEL(4 + 2 * h)};
      J.j[2 * h + 1] = GJob{W2T + (size_t)(h + 2) * 524288, ab2, (h + 2) * 512, PANEL(5 + 2 * h)};
    }
    gemm256_8ph<<<dim3(96, 2, 4), 512, 0, stream>>>(
        Xb, J, -1, nullptr, nullptr, nullptr, nullptr, nullptr, 24576, 512, 1024);
    scores_mfma2<<<dim3(512, 2), 256, 0, stream>>>(
        PANEL(4), PANEL(5), PANEL(6), PANEL(7), S, 2);

    // head 4 -> P0 (Q4), P1 (KV4); heads 0/1 panels dead after scores
    J.j[0] = GJob{W1T + 4 * 524288, ab1, 2048, PANEL(0)};
    J.j[1] = GJob{W2T + 4 * 524288, ab2, 2048, PANEL(1)};
    gemm256_8ph<<<dim3(96, 2, 2), 512, 0, stream>>>(
        Xb, J, -1, nullptr, nullptr, nullptr, nullptr, nullptr, 24576, 512, 1024);

    mid5<0><<<1024, 256, 0, stream>>>(
        S, nullptr, nullptr, nullptr, nullptr, nullptr, nullptr, nullptr, nullptr,
        PANEL(0), PANEL(1), Xb, linW, linb, Af);

    GJobs10 JH{};
    JH.j[0] = GJob{G1T, gb1, 0, PANEL(2)};
    gemm256_8ph<<<dim3(96, 2, 1), 512, 0, stream>>>(
        Xb, JH, 0, prelu, bn1g, bn1b, bn1m, bn1v, 24576, 512, 1024);

    gemm_bt<0><<<dim3(192, 2, 1), 256, 0, stream>>>(
        PANEL(2), G2T, G2T, nullptr, nullptr, 0, PANEL(3), PANEL(3), 24576, 256, 512);

    batch_out4<<<1024, 256, 0, stream>>>(Af, PANEL(3), gb2, bn2g, bn2b, bn2m, bn2v,
                                         (float*)d_out);
  }
#undef PANEL
}